// Round 3
// baseline (858.219 us; speedup 1.0000x reference)
//
#include <hip/hip_runtime.h>
#include <hip/hip_bf16.h>

// Problem constants
#define BATCH 32
#define CIN   256
#define COUT  256
#define HH    56
#define HP    58      // padded
#define NEXP  5
#define HID   65

// Workspace layout (bytes)
#define OFF_S     0                         // 32*256*4      = 32768
#define OFF_ATTN  32768                     // 32*5*4        = 640
#define OFF_WAL   65536                     // 5*9*256*256*4 = 11796480
#define OFF_AGGW  (12u*1024u*1024u)         // 32*9*256*256*2 = 37748736
#define OFF_XPAD  (48u*1024u*1024u)         // 32*58*58*256*2 = 55115776
// total ~ 101 MB

typedef __bf16 bf16x8 __attribute__((ext_vector_type(8)));
typedef float  f32x4  __attribute__((ext_vector_type(4)));

__device__ __forceinline__ unsigned short f2bf(float f) {
    unsigned int u = __float_as_uint(f);
    unsigned int r = (u + 0x7FFFu + ((u >> 16) & 1u)) >> 16;
    return (unsigned short)r;
}

// ---------------------------------------------------------------------------
// k1: zero the 1-px border of xpad (NHWC padded bf16)
// grid (4, 32), block 256
__global__ void border_kernel(unsigned short* __restrict__ xpad) {
    const int b = blockIdx.y, seg = blockIdx.x, tid = threadIdx.x;
    const uint4 z = make_uint4(0, 0, 0, 0);
    if (seg < 2) {
        const int y = seg ? (HP - 1) : 0;
        uint4* p = (uint4*)(xpad + (size_t)((b * HP + y) * HP) * 256);
        for (int i = tid; i < HP * 256 / 8; i += 256) p[i] = z;
    } else {
        const int xx = (seg == 2) ? 0 : (HP - 1);
        for (int i = tid; i < HP * 32; i += 256) {   // 58 rows x 32 uint4
            const int y = i >> 5, sub = i & 31;
            uint4* p = (uint4*)(xpad + (size_t)(((b * HP + y) * HP + xx)) * 256);
            p[sub] = z;
        }
    }
}

// ---------------------------------------------------------------------------
// k2: x (NCHW f32) -> xpad interior (NHWC bf16), fused global-avg-pool partials
// grid (28, 2, 32): (row-pair, channel-half, sample). block 256.
// float2 loads (2 rows of 56 are contiguous within a channel plane).
#define XLP 132   // lds channel pitch (ushort); %4==0 so uint2 reads align
__global__ void xprep_kernel(const float* __restrict__ x,
                             unsigned short* __restrict__ xpad,
                             float* __restrict__ s) {
    const int y0 = blockIdx.x * 2, c0 = blockIdx.y * 128, b = blockIdx.z;
    const int tid = threadIdx.x, lane = tid & 63, wg = tid >> 6;
    __shared__ unsigned short lds[2 * HH * XLP];   // [row][x][c<128]

    #pragma unroll 2
    for (int cc = wg; cc < 128; cc += 4) {
        if (lane < HH) {
            const float2 v = *(const float2*)&x[
                (size_t)((b * 256 + c0 + cc) * HH + y0) * HH + lane * 2];
            const int p = lane * 2;
            const int r0 = p / HH, x0 = p - r0 * HH;
            const int q = p + 1;
            const int r1 = q / HH, x1 = q - r1 * HH;
            lds[(r0 * HH + x0) * XLP + cc] = f2bf(v.x);
            lds[(r1 * HH + x1) * XLP + cc] = f2bf(v.y);
        }
    }
    __syncthreads();
    {   // pooling partial: thread -> (row, channel)
        const int r = tid >> 7, c = tid & 127;
        float sum = 0.f;
        for (int xx = 0; xx < HH; ++xx) {
            const unsigned int u = lds[(r * HH + xx) * XLP + c];
            sum += __uint_as_float(u << 16);
        }
        atomicAdd(&s[b * 256 + c0 + c], sum);
    }
    // write-out: 2 rows x 56 x x 128 ch, 8 B per store
    for (int i = tid; i < 2 * HH * 32; i += 256) {
        const int r = (i >= HH * 32) ? 1 : 0;
        const int rem = i - r * HH * 32;
        const int xx = rem >> 5, cq = (rem & 31) * 4;
        const uint2 v = *(const uint2*)&lds[(r * HH + xx) * XLP + cq];
        *(uint2*)(xpad + (size_t)(((b * HP + y0 + r + 1) * HP + (xx + 1))) * 256
                  + c0 + cq) = v;
    }
}

// ---------------------------------------------------------------------------
// k3: attention MLP.  grid 32, block 128
__global__ void attn_kernel(const float* __restrict__ s,
                            const float* __restrict__ w1,
                            const float* __restrict__ w2,
                            const float* __restrict__ b2,
                            float* __restrict__ attn) {
    const int b = blockIdx.x, tid = threadIdx.x;
    __shared__ float sm[256];
    __shared__ float hm[HID];
    for (int i = tid; i < 256; i += 128) sm[i] = s[b * 256 + i] * (1.f / 3136.f);
    __syncthreads();
    if (tid < HID) {
        float acc = 0.f;
        for (int c = 0; c < 256; ++c) acc += sm[c] * w1[tid * 256 + c];
        hm[tid] = fmaxf(acc, 0.f);
    }
    __syncthreads();
    if (tid < NEXP) {
        float acc = b2[tid];
        for (int j = 0; j < HID; ++j) acc += hm[j] * w2[tid * HID + j];
        attn[b * NEXP + tid] = 1.f / (1.f + expf(-acc));
    }
}

// ---------------------------------------------------------------------------
// k4: w_aligned[e,t,j,i] = sum_o align[e,j,o] * W[e,o,i*9+t]   (fp32)
// grid (18, 4, 5): n-tile(128), j-tile(64), e.  block 256.
__global__ void align_kernel(const float* __restrict__ am,
                             const float* __restrict__ w,
                             float* __restrict__ wal) {
    const int nt = blockIdx.x, jt = blockIdx.y, e = blockIdx.z;
    const int tid = threadIdx.x;
    const int tj = tid >> 5, tn = tid & 31;
    __shared__ float At[64][33];
    __shared__ float Wt[32][128];
    float acc[8][4];
    #pragma unroll
    for (int a = 0; a < 8; ++a)
        #pragma unroll
        for (int c = 0; c < 4; ++c) acc[a][c] = 0.f;

    for (int o0 = 0; o0 < 256; o0 += 32) {
        {   // stage align tile 64x32
            const int row = tid >> 2, col = (tid & 3) * 8;
            const float* src = am + (size_t)((e * 256) + jt * 64 + row) * 256 + o0 + col;
            float4 v0 = *(const float4*)(src);
            float4 v1 = *(const float4*)(src + 4);
            *(float4*)&At[row][col] = v0;
            *(float4*)&At[row][col + 4] = v1;
        }
        {   // stage W tile 32x128
            const int row = tid >> 3, col = (tid & 7) * 16;
            const float* src = w + (size_t)((e * 256) + o0 + row) * 2304 + nt * 128 + col;
            #pragma unroll
            for (int q = 0; q < 4; ++q)
                *(float4*)&Wt[row][col + q * 4] = *(const float4*)(src + q * 4);
        }
        __syncthreads();
        for (int k = 0; k < 32; ++k) {
            float wv[4];
            #pragma unroll
            for (int c = 0; c < 4; ++c) wv[c] = Wt[k][tn * 4 + c];
            #pragma unroll
            for (int a = 0; a < 8; ++a) {
                const float av = At[tj * 8 + a][k];
                #pragma unroll
                for (int c = 0; c < 4; ++c) acc[a][c] += av * wv[c];
            }
        }
        __syncthreads();
    }
    #pragma unroll
    for (int a = 0; a < 8; ++a) {
        const int j = jt * 64 + tj * 8 + a;
        #pragma unroll
        for (int c = 0; c < 4; ++c) {
            const int n = nt * 128 + tn * 4 + c;
            const int t = n % 9, i = n / 9;
            wal[(size_t)(((e * 9 + t) * 256 + j)) * 256 + i] = acc[a][c];
        }
    }
}

// ---------------------------------------------------------------------------
// k5: agg_w[b,t,j,i] (bf16) = sum_e attn[b,e] * wal[e,t,j,i]
// grid 576: t = bx>>6, j-quad = bx&63.  block 256: jl = tid>>6, i4 = (tid&63)*4
__global__ void agg_kernel(const float* __restrict__ wal,
                           const float* __restrict__ attn,
                           unsigned short* __restrict__ aggw) {
    const int t = blockIdx.x >> 6;
    const int j = (blockIdx.x & 63) * 4 + (threadIdx.x >> 6);
    const int i = (threadIdx.x & 63) * 4;
    __shared__ float at[BATCH * NEXP];
    if (threadIdx.x < BATCH * NEXP) at[threadIdx.x] = attn[threadIdx.x];
    float4 wv[NEXP];
    #pragma unroll
    for (int e = 0; e < NEXP; ++e)
        wv[e] = *(const float4*)&wal[(size_t)(((e * 9 + t) * 256 + j)) * 256 + i];
    __syncthreads();
    for (int b = 0; b < BATCH; ++b) {
        float4 acc = make_float4(0.f, 0.f, 0.f, 0.f);
        #pragma unroll
        for (int e = 0; e < NEXP; ++e) {
            const float a = at[b * NEXP + e];
            acc.x += a * wv[e].x; acc.y += a * wv[e].y;
            acc.z += a * wv[e].z; acc.w += a * wv[e].w;
        }
        uint2 pk;
        pk.x = (unsigned)f2bf(acc.x) | ((unsigned)f2bf(acc.y) << 16);
        pk.y = (unsigned)f2bf(acc.z) | ((unsigned)f2bf(acc.w) << 16);
        *(uint2*)&aggw[(size_t)(((b * 9 + t) * 256 + j)) * 256 + i] = pk;
    }
}

// ---------------------------------------------------------------------------
// k6: implicit-GEMM conv. block = 1 sample x 256 couts x 2 output rows (112 px)
// 1D grid 896, XCD-aware remap (28 row-blocks of a sample stay on one XCD so
// aggw[b] is L2-resident). block 256 = 4 waves, wave w -> couts [64w,64w+64).
// LDS layout: 16B units, unit(row,sub,x) = (row*4+sub)*58 + x, where sub = 8-ch
// chunk. B-frag read: 16 ln-lanes hit consecutive units -> bank stride 4,
// 2-way aliasing only (free, m136). Staging writes also <=2-way.
__global__ __launch_bounds__(256, 4) void conv_kernel(
        const unsigned short* __restrict__ xpad,
        const unsigned short* __restrict__ aggw,
        float* __restrict__ out) {
    const int blk = blockIdx.x;
    const int xcd = blk & 7, slot = blk >> 3;       // slot 0..111
    const int b = xcd * 4 + slot / 28;
    const int y0 = (slot % 28) * 2;
    const int tid = threadIdx.x;
    const int wave = tid >> 6, lane = tid & 63;
    const int g = lane >> 4, ln = lane & 15;

    __shared__ unsigned short lds[16 * HP * 8];   // 928 x 16B = 14848 B

    f32x4 acc[4][7];
    #pragma unroll
    for (int mt = 0; mt < 4; ++mt)
        #pragma unroll
        for (int nt = 0; nt < 7; ++nt) acc[mt][nt] = (f32x4){0.f, 0.f, 0.f, 0.f};

    // per-lane B-fragment base byte offsets (ky=kx=0): unit = (yy*4+g)*58 + xx
    int nbase[7];
    #pragma unroll
    for (int nt = 0; nt < 7; ++nt) {
        const int p = nt * 16 + ln;
        const int yy = p / HH, xx = p - yy * HH;
        nbase[nt] = ((yy * 4 + g) * HP + xx) * 16;
    }
    const int mwave = wave * 64;

    #pragma unroll 1
    for (int c0 = 0; c0 < 256; c0 += 32) {
        // stage 4 rows x 58 cols x 32 ch = 928 x 16B
        #pragma unroll
        for (int it = 0; it < 4; ++it) {
            const int idx = it * 256 + tid;
            if (idx < 928) {
                const int row = idx / 232;
                const int rem = idx - row * 232;
                const int col = rem >> 2, sub = rem & 3;
                const uint4 v = *(const uint4*)(xpad +
                    (size_t)(((b * HP + y0 + row) * HP + col)) * 256 + c0 + sub * 8);
                *(uint4*)((char*)lds + ((row * 4 + sub) * HP + col) * 16) = v;
            }
        }
        __syncthreads();

        #pragma unroll
        for (int ky = 0; ky < 3; ++ky) {
            #pragma unroll
            for (int kx = 0; kx < 3; ++kx) {
                const int tap = ky * 3 + kx;
                bf16x8 a[4];
                const unsigned short* ap = aggw +
                    (size_t)(((b * 9 + tap) * 256 + mwave + ln)) * 256 + c0 + g * 8;
                #pragma unroll
                for (int mt = 0; mt < 4; ++mt)
                    a[mt] = *(const bf16x8*)(ap + mt * 16 * 256);
                #pragma unroll
                for (int nt = 0; nt < 7; ++nt) {
                    const bf16x8 bf = *(const bf16x8*)((const char*)lds +
                        nbase[nt] + (ky * 4 * HP + kx) * 16);
                    #pragma unroll
                    for (int mt = 0; mt < 4; ++mt)
                        acc[mt][nt] = __builtin_amdgcn_mfma_f32_16x16x32_bf16(
                            a[mt], bf, acc[mt][nt], 0, 0, 0);
                }
            }
        }
        __syncthreads();
    }

    // epilogue: C/D layout col=lane&15 (pixel), row=(lane>>4)*4+reg (cout)
    #pragma unroll
    for (int mt = 0; mt < 4; ++mt) {
        #pragma unroll
        for (int nt = 0; nt < 7; ++nt) {
            const int p = nt * 16 + ln;
            const int yy = y0 + p / HH, xx = p % HH;
            #pragma unroll
            for (int r = 0; r < 4; ++r) {
                const int cout = mwave + mt * 16 + g * 4 + r;
                out[(size_t)(((b * 256 + cout) * HH + yy)) * HH + xx] = acc[mt][nt][r];
            }
        }
    }
}

// ---------------------------------------------------------------------------
extern "C" void kernel_launch(void* const* d_in, const int* in_sizes, int n_in,
                              void* d_out, int out_size, void* d_ws, size_t ws_size,
                              hipStream_t stream) {
    const float* x      = (const float*)d_in[0];
    const float* weight = (const float*)d_in[1];
    const float* am     = (const float*)d_in[2];
    const float* w1     = (const float*)d_in[3];
    const float* w2     = (const float*)d_in[4];
    const float* b2     = (const float*)d_in[5];
    float* out = (float*)d_out;
    char* ws = (char*)d_ws;

    float* s             = (float*)(ws + OFF_S);
    float* attn          = (float*)(ws + OFF_ATTN);
    float* wal           = (float*)(ws + OFF_WAL);
    unsigned short* aggw = (unsigned short*)(ws + OFF_AGGW);
    unsigned short* xpad = (unsigned short*)(ws + OFF_XPAD);

    hipMemsetAsync(s, 0, BATCH * 256 * sizeof(float), stream);
    border_kernel<<<dim3(4, BATCH), 256, 0, stream>>>(xpad);
    xprep_kernel<<<dim3(28, 2, BATCH), 256, 0, stream>>>(x, xpad, s);
    attn_kernel<<<BATCH, 128, 0, stream>>>(s, w1, w2, b2, attn);
    align_kernel<<<dim3(18, 4, NEXP), 256, 0, stream>>>(am, weight, wal);
    agg_kernel<<<576, 256, 0, stream>>>(wal, attn, aggw);
    conv_kernel<<<896, 256, 0, stream>>>(xpad, aggw, out);
}

// Round 4
// 495.895 us; speedup vs baseline: 1.7306x; 1.7306x over previous
//
#include <hip/hip_runtime.h>
#include <hip/hip_bf16.h>

// Problem constants
#define BATCH 32
#define CIN   256
#define COUT  256
#define HH    56
#define HP    58      // padded
#define NEXP  5
#define HID   65

// Workspace layout (bytes)
#define OFF_S     0                         // 32*256*4      = 32768
#define OFF_ATTN  32768                     // 32*5*4        = 640
#define OFF_WAL   65536                     // 5*9*256*256*4 = 11796480
#define OFF_AGGW  (12u*1024u*1024u)         // 32*9*256*256*2 = 37748736
#define OFF_XPAD  (48u*1024u*1024u)         // 32*58*58*256*2 = 55115776
// total ~ 101 MB

typedef __bf16 bf16x8 __attribute__((ext_vector_type(8)));
typedef float  f32x4  __attribute__((ext_vector_type(4)));

__device__ __forceinline__ unsigned short f2bf(float f) {
    unsigned int u = __float_as_uint(f);
    unsigned int r = (u + 0x7FFFu + ((u >> 16) & 1u)) >> 16;
    return (unsigned short)r;
}

// ---------------------------------------------------------------------------
// k2: x (NCHW f32) -> xpad interior (NHWC bf16), fused pool partials + border
// grid (28, 2, 32): (row-pair, channel-half, sample). block 256.
#define XLP 132   // lds channel pitch (ushort); %4==0 so uint2 reads align
__global__ void xprep_kernel(const float* __restrict__ x,
                             unsigned short* __restrict__ xpad,
                             float* __restrict__ s) {
    const int y0 = blockIdx.x * 2, c0 = blockIdx.y * 128, b = blockIdx.z;
    const int tid = threadIdx.x, lane = tid & 63, wg = tid >> 6;
    __shared__ unsigned short lds[2 * HH * XLP];   // [row][x][c<128]

    // fused border zeroing (1-px frame of xpad, this block's 128 channels)
    {
        const uint4 z = make_uint4(0, 0, 0, 0);
        if (blockIdx.x == 0) {          // padded row 0
            uint4* p = (uint4*)(xpad + (size_t)(b * HP * HP) * 256 + c0);
            for (int i = tid; i < HP * 16; i += 256)   // 58 cols x 16 uint4
                p[(i >> 4) * 32 + (i & 15)] = z;
        }
        if (blockIdx.x == 27) {         // padded row 57
            uint4* p = (uint4*)(xpad + (size_t)((b * HP + 57) * HP) * 256 + c0);
            for (int i = tid; i < HP * 16; i += 256)
                p[(i >> 4) * 32 + (i & 15)] = z;
        }
        // left/right edges of padded rows y0+1, y0+2
        if (tid < 64) {
            const int r = y0 + 1 + (tid >> 5);
            const int cc = ((tid >> 4) & 1) * 57;
            uint4* p = (uint4*)(xpad + (size_t)((b * HP + r) * HP + cc) * 256 + c0);
            p[tid & 15] = z;
        }
    }

    #pragma unroll 2
    for (int cc = wg; cc < 128; cc += 4) {
        if (lane < HH) {
            const float2 v = *(const float2*)&x[
                (size_t)((b * 256 + c0 + cc) * HH + y0) * HH + lane * 2];
            const int p = lane * 2;
            const int r0 = p / HH, x0 = p - r0 * HH;
            const int q = p + 1;
            const int r1 = q / HH, x1 = q - r1 * HH;
            lds[(r0 * HH + x0) * XLP + cc] = f2bf(v.x);
            lds[(r1 * HH + x1) * XLP + cc] = f2bf(v.y);
        }
    }
    __syncthreads();
    {   // pooling partial: thread -> (row, channel)
        const int r = tid >> 7, c = tid & 127;
        float sum = 0.f;
        for (int xx = 0; xx < HH; ++xx) {
            const unsigned int u = lds[(r * HH + xx) * XLP + c];
            sum += __uint_as_float(u << 16);
        }
        atomicAdd(&s[b * 256 + c0 + c], sum);
    }
    // write-out: 2 rows x 56 x x 128 ch, 8 B per store
    for (int i = tid; i < 2 * HH * 32; i += 256) {
        const int r = (i >= HH * 32) ? 1 : 0;
        const int rem = i - r * HH * 32;
        const int xx = rem >> 5, cq = (rem & 31) * 4;
        const uint2 v = *(const uint2*)&lds[(r * HH + xx) * XLP + cq];
        *(uint2*)(xpad + (size_t)(((b * HP + y0 + r + 1) * HP + (xx + 1))) * 256
                  + c0 + cq) = v;
    }
}

// ---------------------------------------------------------------------------
// k3: attention MLP, parallelized over (h, c-half).  grid 32, block 256
__global__ void attn_kernel(const float* __restrict__ s,
                            const float* __restrict__ w1,
                            const float* __restrict__ w2,
                            const float* __restrict__ b2,
                            float* __restrict__ attn) {
    const int b = blockIdx.x, tid = threadIdx.x;
    __shared__ float sm[256];
    __shared__ float part[130];
    __shared__ float hm[HID];
    sm[tid] = s[b * 256 + tid] * (1.f / 3136.f);
    __syncthreads();
    if (tid < 130) {
        const int h = (tid >= 65) ? tid - 65 : tid;
        const int base = (tid >= 65) ? 128 : 0;
        float acc = 0.f;
        #pragma unroll 4
        for (int c = 0; c < 128; ++c) acc += sm[base + c] * w1[h * 256 + base + c];
        part[tid] = acc;
    }
    __syncthreads();
    if (tid < HID) hm[tid] = fmaxf(part[tid] + part[tid + 65], 0.f);
    __syncthreads();
    if (tid < NEXP) {
        float acc = b2[tid];
        for (int j = 0; j < HID; ++j) acc += hm[j] * w2[tid * HID + j];
        attn[b * NEXP + tid] = 1.f / (1.f + expf(-acc));
    }
}

// ---------------------------------------------------------------------------
// k4: w_aligned[e,t,j,i] = sum_o align[e,j,o] * W[e,o,i*9+t]   (fp32)
// grid (18, 4, 5): n-tile(128), j-tile(64), e.  block 256.
__global__ void align_kernel(const float* __restrict__ am,
                             const float* __restrict__ w,
                             float* __restrict__ wal) {
    const int nt = blockIdx.x, jt = blockIdx.y, e = blockIdx.z;
    const int tid = threadIdx.x;
    const int tj = tid >> 5, tn = tid & 31;
    __shared__ float At[64][33];
    __shared__ float Wt[32][128];
    float acc[8][4];
    #pragma unroll
    for (int a = 0; a < 8; ++a)
        #pragma unroll
        for (int c = 0; c < 4; ++c) acc[a][c] = 0.f;

    for (int o0 = 0; o0 < 256; o0 += 32) {
        {   // stage align tile 64x32
            const int row = tid >> 2, col = (tid & 3) * 8;
            const float* src = am + (size_t)((e * 256) + jt * 64 + row) * 256 + o0 + col;
            float4 v0 = *(const float4*)(src);
            float4 v1 = *(const float4*)(src + 4);
            *(float4*)&At[row][col] = v0;
            *(float4*)&At[row][col + 4] = v1;
        }
        {   // stage W tile 32x128
            const int row = tid >> 3, col = (tid & 7) * 16;
            const float* src = w + (size_t)((e * 256) + o0 + row) * 2304 + nt * 128 + col;
            #pragma unroll
            for (int q = 0; q < 4; ++q)
                *(float4*)&Wt[row][col + q * 4] = *(const float4*)(src + q * 4);
        }
        __syncthreads();
        for (int k = 0; k < 32; ++k) {
            float wv[4];
            #pragma unroll
            for (int c = 0; c < 4; ++c) wv[c] = Wt[k][tn * 4 + c];
            #pragma unroll
            for (int a = 0; a < 8; ++a) {
                const float av = At[tj * 8 + a][k];
                #pragma unroll
                for (int c = 0; c < 4; ++c) acc[a][c] += av * wv[c];
            }
        }
        __syncthreads();
    }
    #pragma unroll
    for (int a = 0; a < 8; ++a) {
        const int j = jt * 64 + tj * 8 + a;
        #pragma unroll
        for (int c = 0; c < 4; ++c) {
            const int n = nt * 128 + tn * 4 + c;
            const int t = n % 9, i = n / 9;
            wal[(size_t)(((e * 9 + t) * 256 + j)) * 256 + i] = acc[a][c];
        }
    }
}

// ---------------------------------------------------------------------------
// k5: agg_w[b,t,j,i] (bf16) = sum_e attn[b,e] * wal[e,t,j,i]
// grid 576: t = bx>>6, j-quad = bx&63.  block 256: jl = tid>>6, i4 = (tid&63)*4
__global__ void agg_kernel(const float* __restrict__ wal,
                           const float* __restrict__ attn,
                           unsigned short* __restrict__ aggw) {
    const int t = blockIdx.x >> 6;
    const int j = (blockIdx.x & 63) * 4 + (threadIdx.x >> 6);
    const int i = (threadIdx.x & 63) * 4;
    __shared__ float at[BATCH * NEXP];
    if (threadIdx.x < BATCH * NEXP) at[threadIdx.x] = attn[threadIdx.x];
    float4 wv[NEXP];
    #pragma unroll
    for (int e = 0; e < NEXP; ++e)
        wv[e] = *(const float4*)&wal[(size_t)(((e * 9 + t) * 256 + j)) * 256 + i];
    __syncthreads();
    for (int b = 0; b < BATCH; ++b) {
        float4 acc = make_float4(0.f, 0.f, 0.f, 0.f);
        #pragma unroll
        for (int e = 0; e < NEXP; ++e) {
            const float a = at[b * NEXP + e];
            acc.x += a * wv[e].x; acc.y += a * wv[e].y;
            acc.z += a * wv[e].z; acc.w += a * wv[e].w;
        }
        uint2 pk;
        pk.x = (unsigned)f2bf(acc.x) | ((unsigned)f2bf(acc.y) << 16);
        pk.y = (unsigned)f2bf(acc.z) | ((unsigned)f2bf(acc.w) << 16);
        *(uint2*)&aggw[(size_t)(((b * 9 + t) * 256 + j)) * 256 + i] = pk;
    }
}

// ---------------------------------------------------------------------------
// k6: implicit-GEMM conv.
// Block = 1 sample x 256 couts x (8 cols x 8 rows = 64 px). Grid 7x7x32 = 1568,
// XCD-swizzled (49 px-blocks of a sample stay on one XCD -> aggw[b] L2-hot).
// 4 waves; wave w -> couts [64w, 64w+64). Per wave: 4mt x 4nt of 16x16x32,
// acc = 64 regs (fits 4 waves/SIMD without spill; launch_bounds(256,3) caps
// alloc at ~170 so the compiler CANNOT spill like round 3).
// n-tile (16 px) = 8 cols x 2 rows; wave px region = 8c x 8r (same for all waves).
// LDS: input slab 10r x 10c x 32ch as 16B units, unit = r*41 + c*4 + sub
// (41-unit row pitch rotates banks; B-reads and stores are structurally
// conflict-free at 8 touches/bank).
__global__ __launch_bounds__(256, 3) void conv_kernel(
        const unsigned short* __restrict__ xpad,
        const unsigned short* __restrict__ aggw,
        float* __restrict__ out) {
    const int blk = blockIdx.x;
    const int xcd = blk & 7, slot = blk >> 3;       // slot 0..195
    const int b = xcd * 4 + slot / 49;
    const int pos = slot % 49;
    const int y0 = (pos / 7) * 8, x0 = (pos % 7) * 8;   // output region origin
    const int tid = threadIdx.x;
    const int wave = tid >> 6, lane = tid & 63;
    const int quad = lane >> 4, ln = lane & 15;

    __shared__ unsigned short lds[410 * 8];   // 410 16B units = 6560 B

    f32x4 acc[4][4];
    #pragma unroll
    for (int mt = 0; mt < 4; ++mt)
        #pragma unroll
        for (int nt = 0; nt < 4; ++nt) acc[mt][nt] = (f32x4){0.f, 0.f, 0.f, 0.f};

    // B-frag base byte offsets (tap 0,0): px row=(ln>>3)+nt*2, col=ln&7; sub=quad
    int nb[4];
    #pragma unroll
    for (int nt = 0; nt < 4; ++nt)
        nb[nt] = ((((ln >> 3) + nt * 2) * 41 + (ln & 7) * 4 + quad)) * 16;

    const unsigned short* ap0 = aggw +
        (size_t)(b * 9 * 65536 + (wave * 64 + ln) * 256 + quad * 8);

    #pragma unroll 1
    for (int c0 = 0; c0 < 256; c0 += 32) {
        // stage 10r x 10c x 32ch = 400 x 16B units
        for (int u = tid; u < 400; u += 256) {
            const int r = u / 40, rem = u - r * 40;
            const int c = rem >> 2, sub = rem & 3;
            const uint4 v = *(const uint4*)(xpad +
                (size_t)(((b * HP + y0 + r) * HP + x0 + c)) * 256 + c0 + sub * 8);
            *(uint4*)((char*)lds + (r * 41 + c * 4 + sub) * 16) = v;
        }
        __syncthreads();

        #pragma unroll
        for (int ky = 0; ky < 3; ++ky) {
            #pragma unroll
            for (int kx = 0; kx < 3; ++kx) {
                const int tap = ky * 3 + kx;
                const unsigned short* ap = ap0 + tap * 65536 + c0;
                bf16x8 a[4];
                #pragma unroll
                for (int mt = 0; mt < 4; ++mt)
                    a[mt] = *(const bf16x8*)(ap + mt * 16 * 256);
                #pragma unroll
                for (int nt = 0; nt < 4; ++nt) {
                    const bf16x8 bf = *(const bf16x8*)((const char*)lds +
                        nb[nt] + (ky * 41 + kx * 4) * 16);
                    #pragma unroll
                    for (int mt = 0; mt < 4; ++mt)
                        acc[mt][nt] = __builtin_amdgcn_mfma_f32_16x16x32_bf16(
                            a[mt], bf, acc[mt][nt], 0, 0, 0);
                }
            }
        }
        __syncthreads();
    }

    // epilogue: C/D layout col(n)=lane&15 -> pixel, row(m)=quad*4+reg -> cout
    #pragma unroll
    for (int mt = 0; mt < 4; ++mt) {
        #pragma unroll
        for (int nt = 0; nt < 4; ++nt) {
            const int yy = y0 + (ln >> 3) + nt * 2;
            const int xx = x0 + (ln & 7);
            #pragma unroll
            for (int r = 0; r < 4; ++r) {
                const int cout = wave * 64 + mt * 16 + quad * 4 + r;
                out[(size_t)(((b * 256 + cout) * HH + yy)) * HH + xx] = acc[mt][nt][r];
            }
        }
    }
}

// ---------------------------------------------------------------------------
extern "C" void kernel_launch(void* const* d_in, const int* in_sizes, int n_in,
                              void* d_out, int out_size, void* d_ws, size_t ws_size,
                              hipStream_t stream) {
    const float* x      = (const float*)d_in[0];
    const float* weight = (const float*)d_in[1];
    const float* am     = (const float*)d_in[2];
    const float* w1     = (const float*)d_in[3];
    const float* w2     = (const float*)d_in[4];
    const float* b2     = (const float*)d_in[5];
    float* out = (float*)d_out;
    char* ws = (char*)d_ws;

    float* s             = (float*)(ws + OFF_S);
    float* attn          = (float*)(ws + OFF_ATTN);
    float* wal           = (float*)(ws + OFF_WAL);
    unsigned short* aggw = (unsigned short*)(ws + OFF_AGGW);
    unsigned short* xpad = (unsigned short*)(ws + OFF_XPAD);

    hipMemsetAsync(s, 0, BATCH * 256 * sizeof(float), stream);
    xprep_kernel<<<dim3(28, 2, BATCH), 256, 0, stream>>>(x, xpad, s);
    attn_kernel<<<BATCH, 256, 0, stream>>>(s, w1, w2, b2, attn);
    align_kernel<<<dim3(18, 4, NEXP), 256, 0, stream>>>(am, weight, wal);
    agg_kernel<<<576, 256, 0, stream>>>(wal, attn, aggw);
    conv_kernel<<<1568, 256, 0, stream>>>(xpad, aggw, out);
}